// Round 6
// baseline (664.854 us; speedup 1.0000x reference)
//
#include <hip/hip_runtime.h>
#include <hip/hip_bf16.h>
#include <stdint.h>

typedef unsigned short u16;
typedef __attribute__((ext_vector_type(8))) short short8;   // 8 bf16 (4 VGPRs)
typedef __attribute__((ext_vector_type(4))) float f32x4;

union B8 { short8 v; u16 u[8]; };
union U4 { unsigned long long q; u16 u[4]; };

__device__ __forceinline__ float b2f(u16 b) {
  union { unsigned int i; float f; } x; x.i = ((unsigned int)b) << 16; return x.f;
}
__device__ __forceinline__ u16 f2b(float f) {
  __hip_bfloat16 h = __float2bfloat16(f);
  return *reinterpret_cast<u16*>(&h);
}

// async global->LDS, 16B/lane, LDS dest = wave-uniform base + lane*16 [m97]
#define GLOAD_LDS16(gp, lp)                                                  \
  __builtin_amdgcn_global_load_lds(                                          \
      (const __attribute__((address_space(1))) unsigned int*)(gp),           \
      (__attribute__((address_space(3))) unsigned int*)(lp), 16, 0, 0)

// ---------------- convert fp32 -> bf16 (elementwise, n % 1024 == 0) --------
__global__ __launch_bounds__(256) void cvt_f2b(const float* __restrict__ src,
                                               u16* __restrict__ dst) {
  size_t i = ((size_t)blockIdx.x * 256 + threadIdx.x) * 4;
  f32x4 v = *(const f32x4*)(src + i);
  U4 o;
#pragma unroll
  for (int j = 0; j < 4; ++j) o.u[j] = f2b(v[j]);
  *(unsigned long long*)(dst + i) = o.q;
}

// ---------------- convert + transpose: fp32 W[K][N] -> bf16 WT[N][K] -------
__global__ __launch_bounds__(256) void convt_w(const float* __restrict__ W,
                                               u16* __restrict__ WT,
                                               int K, int N) {
  int k  = blockIdx.x * 64 + (threadIdx.x & 63);
  int n8 = blockIdx.y * 32 + (threadIdx.x >> 6) * 8;
  const float* p = W + (size_t)k * N + n8;
  f32x4 a = *(const f32x4*)(p);
  f32x4 b = *(const f32x4*)(p + 4);
#pragma unroll
  for (int j = 0; j < 4; ++j) WT[(size_t)(n8 + j) * K + k] = f2b(a[j]);
#pragma unroll
  for (int j = 0; j < 4; ++j) WT[(size_t)(n8 + 4 + j) * K + k] = f2b(b[j]);
}

// ---------------- GEMM: C = A[M][K] @ BT[N][K]^T, bf16 in, fp32 acc --------
// 128x128 tile, BK=32, global_load_lds width-16.
// Staging permutation: lane l stages the element fragment-lane l consumes
// (srow=l&15, scol=(l>>4)*8)  =>  ds_read addr = base + lane*16: 0 conflicts.
// XCD swizzle: blocks on one XCD share a 4-tile column band (B L2-resident).
__global__ __launch_bounds__(256) void gemm_bf16(
    const u16* __restrict__ A, const u16* __restrict__ BT,
    const float* __restrict__ bias, const float* __restrict__ addf,
    const u16* __restrict__ mulg,
    u16* __restrict__ Cb, float* __restrict__ Cf, int M, int N, int K)
{
  __shared__ __attribute__((aligned(16))) u16 As[128 * 32];
  __shared__ __attribute__((aligned(16))) u16 Bs[128 * 32];
  int tid = threadIdx.x;

  // XCD-aware remap (dispatch round-robins blocks over 8 XCDs)
  int bx = blockIdx.x, by = blockIdx.y;
  if ((gridDim.x & 7) == 0) {
    int id = by * gridDim.x + bx;
    int cw = gridDim.x >> 3;
    int xcd = id & 7, w2 = id >> 3;
    bx = xcd * cw + (w2 % cw);
    by = w2 / cw;
  }
  int m0 = by * 128, n0 = bx * 128;

  int wave = tid >> 6, lane = tid & 63;
  int wm = (wave >> 1) * 64, wn = (wave & 1) * 64;
  int quad = lane >> 4, r16 = lane & 15;
  int seg0 = wave * 2, seg1 = wave * 2 + 1;     // 16-row segments
  int srow = lane & 15, scol = (lane >> 4) * 8; // fragment-order staging

  const u16* a0 = A  + (size_t)(m0 + seg0 * 16 + srow) * K + scol;
  const u16* a1 = A  + (size_t)(m0 + seg1 * 16 + srow) * K + scol;
  const u16* b0 = BT + (size_t)(n0 + seg0 * 16 + srow) * K + scol;
  const u16* b1 = BT + (size_t)(n0 + seg1 * 16 + srow) * K + scol;

  int sa = wm >> 4, sb = wn >> 4;               // wave's fragment segments
  f32x4 acc[4][4] = {};

  for (int k0 = 0; k0 < K; k0 += 32) {
    GLOAD_LDS16(a0 + k0, As + seg0 * 512);
    GLOAD_LDS16(a1 + k0, As + seg1 * 512);
    GLOAD_LDS16(b0 + k0, Bs + seg0 * 512);
    GLOAD_LDS16(b1 + k0, Bs + seg1 * 512);
    __syncthreads();
    short8 af[4], bfr[4];
#pragma unroll
    for (int i = 0; i < 4; ++i)
      af[i] = *(const short8*)(&As[(sa + i) * 512 + lane * 8]);
#pragma unroll
    for (int j = 0; j < 4; ++j)
      bfr[j] = *(const short8*)(&Bs[(sb + j) * 512 + lane * 8]);
#pragma unroll
    for (int i = 0; i < 4; ++i)
#pragma unroll
      for (int j = 0; j < 4; ++j)
        acc[i][j] = __builtin_amdgcn_mfma_f32_16x16x32_bf16(af[i], bfr[j], acc[i][j], 0, 0, 0);
    __syncthreads();
  }

  // C/D layout: col = lane&15, row = quad*4 + reg   [m89-verified]
#pragma unroll
  for (int i = 0; i < 4; ++i) {
    int row = m0 + wm + i * 16 + quad * 4;
#pragma unroll
    for (int j = 0; j < 4; ++j) {
      int col = n0 + wn + j * 16 + r16;
      float bv = bias ? bias[col] : 0.f;
#pragma unroll
      for (int r = 0; r < 4; ++r) {
        float v = acc[i][j][r] + bv;
        size_t o = (size_t)(row + r) * N + col;
        if (addf) v += addf[o];
        if (mulg) { float g = b2f(mulg[o]); v *= g / (1.f + __expf(-g)); }
        if (Cb) Cb[o] = f2b(v); else Cf[o] = v;
      }
    }
  }
}

// ---------------- product-key retrieval (wave-parallel butterfly top-k) ----
// block = token, wave = head. Butterfly argmax: tie-break lowest index (jax).
__global__ __launch_bounds__(256) void retrieve_k(
    const u16*  __restrict__ q,     // bf16 [4096][512] = [t][p(2)][h(4)][n(64)]
    const float* __restrict__ keys, // fp32 [4][64][2][64]
    int* __restrict__ idx_out,      // [4096][4][8]
    float* __restrict__ p_out)      // [4096][4][8]
{
  __shared__ float tv[4][2][8];
  __shared__ int   ti[4][2][8];
  int t = blockIdx.x;
  int w = threadIdx.x >> 6, lane = threadIdx.x & 63;

#pragma unroll
  for (int p = 0; p < 2; ++p) {
    const u16*   qp = q + (size_t)t * 512 + p * 256 + w * 64;
    const float* kp = keys + (size_t)((w * 64 + lane) * 2 + p) * 64;
    float s = 0.f;
#pragma unroll
    for (int n = 0; n < 64; n += 8) {
      B8 qv; qv.v = *(const short8*)(qp + n);
      f32x4 k0 = *(const f32x4*)(kp + n);
      f32x4 k1 = *(const f32x4*)(kp + n + 4);
#pragma unroll
      for (int c = 0; c < 4; ++c) s += b2f(qv.u[c]) * k0[c];
#pragma unroll
      for (int c = 0; c < 4; ++c) s += b2f(qv.u[4 + c]) * k1[c];
    }
    float v = s; int vi = lane;
#pragma unroll
    for (int r = 0; r < 8; ++r) {
      float mv = v; int mi = vi;
#pragma unroll
      for (int off = 32; off; off >>= 1) {
        float ov = __shfl_xor(mv, off);
        int   oi = __shfl_xor(mi, off);
        if (ov > mv || (ov == mv && oi < mi)) { mv = ov; mi = oi; }
      }
      if (lane == 0) { tv[w][p][r] = mv; ti[w][p][r] = mi; }
      if (vi == mi) v = -3.0e38f;   // remove winner
    }
  }
  __syncthreads();
  // combos: lane = a*8 + b, matches reference reshape ordering
  float v2 = tv[w][0][lane >> 3] + tv[w][1][lane & 7];
  int vi2 = lane;
  float s8[8]; int x8[8];
#pragma unroll
  for (int r = 0; r < 8; ++r) {
    float mv = v2; int mi = vi2;
#pragma unroll
    for (int off = 32; off; off >>= 1) {
      float ov = __shfl_xor(mv, off);
      int   oi = __shfl_xor(mi, off);
      if (ov > mv || (ov == mv && oi < mi)) { mv = ov; mi = oi; }
    }
    s8[r] = mv;                      // all lanes hold the result
    x8[r] = ti[w][0][mi >> 3] * 64 + ti[w][1][mi & 7];
    if (vi2 == mi) v2 = -3.0e38f;
  }
  if (lane == 0) {
    float m = s8[0], sum = 0.f;
#pragma unroll
    for (int r = 0; r < 8; ++r) sum += __expf(s8[r] - m);
#pragma unroll
    for (int r = 0; r < 8; ++r) {
      int o = (t * 4 + w) * 8 + r;
      p_out[o]   = __expf(s8[r] - m) / sum;
      idx_out[o] = x8[r];
    }
  }
}

// ---------------- expert gather + weighted sum (bf16 tables, fp32 acc) -----
__global__ __launch_bounds__(256) void expert_k(
    const u16* __restrict__ xb, const u16* __restrict__ downb,
    const u16* __restrict__ upb,
    const int* __restrict__ idx, const float* __restrict__ probs,
    float* __restrict__ es)     // [4096][1024] fp32
{
  __shared__ float acc_s[4][1024];   // 16 KB
  int t = blockIdx.x;
  int w = threadIdx.x >> 6, lane = threadIdx.x & 63;
  const size_t tb = (size_t)t * 1024;
  const int lo = lane * 8;

  B8 xv0, xv1;
  xv0.v = *(const short8*)(xb + tb + lo);
  xv1.v = *(const short8*)(xb + tb + 512 + lo);
  float xf[16];
#pragma unroll
  for (int c = 0; c < 8; ++c) { xf[c] = b2f(xv0.u[c]); xf[8 + c] = b2f(xv1.u[c]); }

  float a[16] = {};
#pragma unroll
  for (int e8 = 0; e8 < 8; ++e8) {
    int e = w * 8 + e8;
    int id = idx[t * 32 + e];
    const u16* dp = downb + (size_t)id * 1024;
    B8 d0, d1;
    d0.v = *(const short8*)(dp + lo);
    d1.v = *(const short8*)(dp + 512 + lo);
    float part = 0.f;
#pragma unroll
    for (int c = 0; c < 8; ++c)
      part += xf[c] * b2f(d0.u[c]) + xf[8 + c] * b2f(d1.u[c]);
#pragma unroll
    for (int off = 32; off; off >>= 1) part += __shfl_xor(part, off);
    float gate = (part / (1.f + __expf(-part))) * probs[t * 32 + e];
    const u16* upp = upb + (size_t)id * 1024;
    B8 u0, u1;
    u0.v = *(const short8*)(upp + lo);
    u1.v = *(const short8*)(upp + 512 + lo);
#pragma unroll
    for (int c = 0; c < 8; ++c) {
      a[c]     += gate * b2f(u0.u[c]);
      a[8 + c] += gate * b2f(u1.u[c]);
    }
  }
#pragma unroll
  for (int c = 0; c < 8; ++c) {
    acc_s[w][lo + c]       = a[c];
    acc_s[w][512 + lo + c] = a[8 + c];
  }
  __syncthreads();
  int d0i = threadIdx.x * 4;
  f32x4 s0 = *(const f32x4*)(&acc_s[0][d0i]);
  f32x4 s1 = *(const f32x4*)(&acc_s[1][d0i]);
  f32x4 s2 = *(const f32x4*)(&acc_s[2][d0i]);
  f32x4 s3 = *(const f32x4*)(&acc_s[3][d0i]);
  f32x4 o;
#pragma unroll
  for (int c = 0; c < 4; ++c) o[c] = (s0[c] + s1[c]) + (s2[c] + s3[c]);
  *(f32x4*)(es + tb + d0i) = o;
}

extern "C" void kernel_launch(void* const* d_in, const int* in_sizes, int n_in,
                              void* d_out, int out_size, void* d_ws, size_t ws_size,
                              hipStream_t stream)
{
  const float* x    = (const float*)d_in[0];
  const float* Wg   = (const float*)d_in[1];
  const float* bg   = (const float*)d_in[2];
  const float* Wu   = (const float*)d_in[3];
  const float* bu   = (const float*)d_in[4];
  const float* Wd   = (const float*)d_in[5];
  const float* bd   = (const float*)d_in[6];
  const float* Wq   = (const float*)d_in[7];
  const float* keys = (const float*)d_in[8];
  const float* down = (const float*)d_in[9];
  const float* up   = (const float*)d_in[10];
  float* out = (float*)d_out;

  // --- workspace layout ---
  const size_t MB = 1048576;
  char* ws = (char*)d_ws;
  u16*   xb    = (u16*)(ws);                 // 8 MB  bf16 x [4096][1024]
  u16*   WgT   = (u16*)(ws + 8  * MB);       // 8 MB  bf16 [4096][1024]
  u16*   WuT   = (u16*)(ws + 16 * MB);       // 8 MB
  u16*   WdT   = (u16*)(ws + 24 * MB);       // 8 MB  bf16 [1024][4096]
  float* es    = (float*)(ws + 32 * MB);     // 16 MB fp32 [4096][1024]
  u16*   WqT   = (u16*)(ws + 32 * MB);       // 1 MB, aliases es head (dead first)
  u16*   qb    = (u16*)(ws + 34 * MB);       // 4 MB, aliases es (dead first)
  int*   idxb  = (int*)(ws + 48 * MB);       // 512 KB
  float* prb   = (float*)(ws + 48 * MB + 512 * 1024);
  u16*   downb = (u16*)(ws + 49 * MB);       // 8 MB bf16 [4096][1024]
  u16*   upb   = (u16*)(ws + 57 * MB);       // 8 MB
  u16*   gb    = (u16*)(ws + 65 * MB);       // chunk_rows x 4096 bf16

  size_t avail = ws_size > 65 * MB ? ws_size - 65 * MB : 0;
  int rows = 4096;                           // rows per MLP chunk
  while (rows > 128 && (size_t)rows * 4096 * 2 > avail) rows >>= 1;

  // conversions (fp32 -> bf16; weights fused with transpose)
  cvt_f2b<<<4096, 256, 0, stream>>>(x, xb);
  cvt_f2b<<<4096, 256, 0, stream>>>(down, downb);
  cvt_f2b<<<4096, 256, 0, stream>>>(up, upb);
  convt_w<<<dim3(16, 16),  256, 0, stream>>>(Wq, WqT, 1024, 512);
  convt_w<<<dim3(16, 128), 256, 0, stream>>>(Wg, WgT, 1024, 4096);
  convt_w<<<dim3(16, 128), 256, 0, stream>>>(Wu, WuT, 1024, 4096);
  convt_w<<<dim3(64, 32),  256, 0, stream>>>(Wd, WdT, 4096, 1024);

  // retrieval chain: q = x@Wq -> topk experts -> es
  gemm_bf16<<<dim3(4, 32), 256, 0, stream>>>(xb, WqT, nullptr, nullptr, nullptr,
                                             qb, nullptr, 4096, 512, 1024);
  retrieve_k<<<4096, 256, 0, stream>>>(qb, keys, idxb, prb);
  expert_k<<<4096, 256, 0, stream>>>(xb, downb, upb, idxb, prb, es);

  // MLP chain, chunked over M: g=x@Wg+bg; h1=silu(g)*(x@Wu+bu); out=h1@Wd+bd+es
  for (int m0c = 0; m0c < 4096; m0c += rows) {
    int gy = rows / 128;
    gemm_bf16<<<dim3(32, gy), 256, 0, stream>>>(xb + (size_t)m0c * 1024, WgT, bg,
                                                nullptr, nullptr, gb, nullptr,
                                                rows, 4096, 1024);
    gemm_bf16<<<dim3(32, gy), 256, 0, stream>>>(xb + (size_t)m0c * 1024, WuT, bu,
                                                nullptr, gb, gb, nullptr,
                                                rows, 4096, 1024);
    gemm_bf16<<<dim3(8, gy), 256, 0, stream>>>(gb, WdT, bd, es + (size_t)m0c * 1024,
                                               nullptr, nullptr, out + (size_t)m0c * 1024,
                                               rows, 1024, 4096);
  }
}

// Round 7
// 602.783 us; speedup vs baseline: 1.1030x; 1.1030x over previous
//
#include <hip/hip_runtime.h>
#include <hip/hip_bf16.h>
#include <stdint.h>

typedef unsigned short u16;
typedef __attribute__((ext_vector_type(8))) short short8;   // 8 bf16 (4 VGPRs)
typedef __attribute__((ext_vector_type(4))) float f32x4;

union B8 { short8 v; u16 u[8]; };
union U4 { unsigned long long q; u16 u[4]; };

__device__ __forceinline__ float b2f(u16 b) {
  union { unsigned int i; float f; } x; x.i = ((unsigned int)b) << 16; return x.f;
}
__device__ __forceinline__ u16 f2b(float f) {
  __hip_bfloat16 h = __float2bfloat16(f);
  return *reinterpret_cast<u16*>(&h);
}

// async global->LDS, 16B/lane, LDS dest = wave-uniform base + lane*16 [m97]
#define GLOAD_LDS16(gp, lp)                                                  \
  __builtin_amdgcn_global_load_lds(                                          \
      (const __attribute__((address_space(1))) unsigned int*)(gp),           \
      (__attribute__((address_space(3))) unsigned int*)(lp), 16, 0, 0)

// ---------------- convert fp32 -> bf16 (elementwise, n % 1024 == 0) --------
__global__ __launch_bounds__(256) void cvt_f2b(const float* __restrict__ src,
                                               u16* __restrict__ dst) {
  size_t i = ((size_t)blockIdx.x * 256 + threadIdx.x) * 4;
  f32x4 v = *(const f32x4*)(src + i);
  U4 o;
#pragma unroll
  for (int j = 0; j < 4; ++j) o.u[j] = f2b(v[j]);
  *(unsigned long long*)(dst + i) = o.q;
}

// ---------------- convert + transpose: fp32 W[K][N] -> bf16 WT[N][K] -------
__global__ __launch_bounds__(256) void convt_w(const float* __restrict__ W,
                                               u16* __restrict__ WT,
                                               int K, int N) {
  int k  = blockIdx.x * 64 + (threadIdx.x & 63);
  int n8 = blockIdx.y * 32 + (threadIdx.x >> 6) * 8;
  const float* p = W + (size_t)k * N + n8;
  f32x4 a = *(const f32x4*)(p);
  f32x4 b = *(const f32x4*)(p + 4);
#pragma unroll
  for (int j = 0; j < 4; ++j) WT[(size_t)(n8 + j) * K + k] = f2b(a[j]);
#pragma unroll
  for (int j = 0; j < 4; ++j) WT[(size_t)(n8 + 4 + j) * K + k] = f2b(b[j]);
}

// ---------------- GEMM: C = A[M][K] @ BT[N][K]^T, bf16 in, fp32 acc --------
// R5 structure (best measured): 128x128, BK=32, coalesced 64B staging runs.
__global__ __launch_bounds__(256) void gemm_bf16(
    const u16* __restrict__ A, const u16* __restrict__ BT,
    const float* __restrict__ bias, const float* __restrict__ addf,
    u16* __restrict__ Cb, float* __restrict__ Cf, int M, int N, int K)
{
  __shared__ __attribute__((aligned(16))) u16 As[128 * 32];
  __shared__ __attribute__((aligned(16))) u16 Bs[128 * 32];
  int tid = threadIdx.x;
  int m0 = blockIdx.y * 128, n0 = blockIdx.x * 128;
  int wave = tid >> 6, lane = tid & 63;
  int wm = (wave >> 1) * 64, wn = (wave & 1) * 64;
  int quad = lane >> 4, r16 = lane & 15;
  int seg0 = wave * 2, seg1 = wave * 2 + 1;     // 16-row segments
  int srow = lane >> 2, scol = (lane & 3) * 8;  // 64B-run coalesced staging

  const u16* a0 = A  + (size_t)(m0 + seg0 * 16 + srow) * K + scol;
  const u16* a1 = A  + (size_t)(m0 + seg1 * 16 + srow) * K + scol;
  const u16* b0 = BT + (size_t)(n0 + seg0 * 16 + srow) * K + scol;
  const u16* b1 = BT + (size_t)(n0 + seg1 * 16 + srow) * K + scol;

  f32x4 acc[4][4] = {};

  for (int k0 = 0; k0 < K; k0 += 32) {
    GLOAD_LDS16(a0 + k0, As + seg0 * 512);
    GLOAD_LDS16(a1 + k0, As + seg1 * 512);
    GLOAD_LDS16(b0 + k0, Bs + seg0 * 512);
    GLOAD_LDS16(b1 + k0, Bs + seg1 * 512);
    __syncthreads();
    short8 af[4], bfr[4];
#pragma unroll
    for (int i = 0; i < 4; ++i)
      af[i] = *(const short8*)(&As[(wm + i * 16 + r16) * 32 + quad * 8]);
#pragma unroll
    for (int j = 0; j < 4; ++j)
      bfr[j] = *(const short8*)(&Bs[(wn + j * 16 + r16) * 32 + quad * 8]);
#pragma unroll
    for (int i = 0; i < 4; ++i)
#pragma unroll
      for (int j = 0; j < 4; ++j)
        acc[i][j] = __builtin_amdgcn_mfma_f32_16x16x32_bf16(af[i], bfr[j], acc[i][j], 0, 0, 0);
    __syncthreads();
  }

  // C/D layout: col = lane&15, row = quad*4 + reg   [m89-verified]
#pragma unroll
  for (int i = 0; i < 4; ++i) {
    int row = m0 + wm + i * 16 + quad * 4;
#pragma unroll
    for (int j = 0; j < 4; ++j) {
      int col = n0 + wn + j * 16 + r16;
      float bv = bias ? bias[col] : 0.f;
#pragma unroll
      for (int r = 0; r < 4; ++r) {
        float v = acc[i][j][r] + bv;
        size_t o = (size_t)(row + r) * N + col;
        if (addf) v += addf[o];
        if (Cb) Cb[o] = f2b(v); else Cf[o] = v;
      }
    }
  }
}

// ------- fused gate+up GEMM: H = silu(A@Bg^T + bg) * (A@Bu^T + bu) ---------
// Stages A once for both products; h1 computed in-register (no gb round-trip).
__global__ __launch_bounds__(256) void gemm_gu(
    const u16* __restrict__ A, const u16* __restrict__ BgT,
    const u16* __restrict__ BuT,
    const float* __restrict__ bg, const float* __restrict__ bu,
    u16* __restrict__ H, int M, int N, int K)
{
  __shared__ __attribute__((aligned(16))) u16 As[128 * 32];
  __shared__ __attribute__((aligned(16))) u16 Gs[128 * 32];
  __shared__ __attribute__((aligned(16))) u16 Us[128 * 32];
  int tid = threadIdx.x;
  int m0 = blockIdx.y * 128, n0 = blockIdx.x * 128;
  int wave = tid >> 6, lane = tid & 63;
  int wm = (wave >> 1) * 64, wn = (wave & 1) * 64;
  int quad = lane >> 4, r16 = lane & 15;
  int seg0 = wave * 2, seg1 = wave * 2 + 1;
  int srow = lane >> 2, scol = (lane & 3) * 8;

  const u16* a0 = A   + (size_t)(m0 + seg0 * 16 + srow) * K + scol;
  const u16* a1 = A   + (size_t)(m0 + seg1 * 16 + srow) * K + scol;
  const u16* g0 = BgT + (size_t)(n0 + seg0 * 16 + srow) * K + scol;
  const u16* g1 = BgT + (size_t)(n0 + seg1 * 16 + srow) * K + scol;
  const u16* u0 = BuT + (size_t)(n0 + seg0 * 16 + srow) * K + scol;
  const u16* u1 = BuT + (size_t)(n0 + seg1 * 16 + srow) * K + scol;

  f32x4 ag[4][4] = {}, au[4][4] = {};

  for (int k0 = 0; k0 < K; k0 += 32) {
    GLOAD_LDS16(a0 + k0, As + seg0 * 512);
    GLOAD_LDS16(a1 + k0, As + seg1 * 512);
    GLOAD_LDS16(g0 + k0, Gs + seg0 * 512);
    GLOAD_LDS16(g1 + k0, Gs + seg1 * 512);
    GLOAD_LDS16(u0 + k0, Us + seg0 * 512);
    GLOAD_LDS16(u1 + k0, Us + seg1 * 512);
    __syncthreads();
    short8 af[4], bfr[4];
#pragma unroll
    for (int i = 0; i < 4; ++i)
      af[i] = *(const short8*)(&As[(wm + i * 16 + r16) * 32 + quad * 8]);
#pragma unroll
    for (int j = 0; j < 4; ++j)
      bfr[j] = *(const short8*)(&Gs[(wn + j * 16 + r16) * 32 + quad * 8]);
#pragma unroll
    for (int i = 0; i < 4; ++i)
#pragma unroll
      for (int j = 0; j < 4; ++j)
        ag[i][j] = __builtin_amdgcn_mfma_f32_16x16x32_bf16(af[i], bfr[j], ag[i][j], 0, 0, 0);
#pragma unroll
    for (int j = 0; j < 4; ++j)
      bfr[j] = *(const short8*)(&Us[(wn + j * 16 + r16) * 32 + quad * 8]);
#pragma unroll
    for (int i = 0; i < 4; ++i)
#pragma unroll
      for (int j = 0; j < 4; ++j)
        au[i][j] = __builtin_amdgcn_mfma_f32_16x16x32_bf16(af[i], bfr[j], au[i][j], 0, 0, 0);
    __syncthreads();
  }

#pragma unroll
  for (int i = 0; i < 4; ++i) {
    int row = m0 + wm + i * 16 + quad * 4;
#pragma unroll
    for (int j = 0; j < 4; ++j) {
      int col = n0 + wn + j * 16 + r16;
      float bgv = bg[col], buv = bu[col];
#pragma unroll
      for (int r = 0; r < 4; ++r) {
        float g = ag[i][j][r] + bgv;
        float u = au[i][j][r] + buv;
        float h = (g / (1.f + __expf(-g))) * u;
        H[(size_t)(row + r) * N + col] = f2b(h);
      }
    }
  }
}

// ---------------- product-key retrieval (wave-parallel butterfly top-k) ----
__global__ __launch_bounds__(256) void retrieve_k(
    const u16*  __restrict__ q,     // bf16 [4096][512] = [t][p(2)][h(4)][n(64)]
    const float* __restrict__ keys, // fp32 [4][64][2][64]
    int* __restrict__ idx_out,      // [4096][4][8]
    float* __restrict__ p_out)      // [4096][4][8]
{
  __shared__ float tv[4][2][8];
  __shared__ int   ti[4][2][8];
  int t = blockIdx.x;
  int w = threadIdx.x >> 6, lane = threadIdx.x & 63;

#pragma unroll
  for (int p = 0; p < 2; ++p) {
    const u16*   qp = q + (size_t)t * 512 + p * 256 + w * 64;
    const float* kp = keys + (size_t)((w * 64 + lane) * 2 + p) * 64;
    float s = 0.f;
#pragma unroll
    for (int n = 0; n < 64; n += 8) {
      B8 qv; qv.v = *(const short8*)(qp + n);
      f32x4 k0 = *(const f32x4*)(kp + n);
      f32x4 k1 = *(const f32x4*)(kp + n + 4);
#pragma unroll
      for (int c = 0; c < 4; ++c) s += b2f(qv.u[c]) * k0[c];
#pragma unroll
      for (int c = 0; c < 4; ++c) s += b2f(qv.u[4 + c]) * k1[c];
    }
    float v = s; int vi = lane;
#pragma unroll
    for (int r = 0; r < 8; ++r) {
      float mv = v; int mi = vi;
#pragma unroll
      for (int off = 32; off; off >>= 1) {
        float ov = __shfl_xor(mv, off);
        int   oi = __shfl_xor(mi, off);
        if (ov > mv || (ov == mv && oi < mi)) { mv = ov; mi = oi; }
      }
      if (lane == 0) { tv[w][p][r] = mv; ti[w][p][r] = mi; }
      if (vi == mi) v = -3.0e38f;
    }
  }
  __syncthreads();
  float v2 = tv[w][0][lane >> 3] + tv[w][1][lane & 7];
  int vi2 = lane;
  float s8[8]; int x8[8];
#pragma unroll
  for (int r = 0; r < 8; ++r) {
    float mv = v2; int mi = vi2;
#pragma unroll
    for (int off = 32; off; off >>= 1) {
      float ov = __shfl_xor(mv, off);
      int   oi = __shfl_xor(mi, off);
      if (ov > mv || (ov == mv && oi < mi)) { mv = ov; mi = oi; }
    }
    s8[r] = mv;
    x8[r] = ti[w][0][mi >> 3] * 64 + ti[w][1][mi & 7];
    if (vi2 == mi) v2 = -3.0e38f;
  }
  if (lane == 0) {
    float m = s8[0], sum = 0.f;
#pragma unroll
    for (int r = 0; r < 8; ++r) sum += __expf(s8[r] - m);
#pragma unroll
    for (int r = 0; r < 8; ++r) {
      int o = (t * 4 + w) * 8 + r;
      p_out[o]   = __expf(s8[r] - m) / sum;
      idx_out[o] = x8[r];
    }
  }
}

// ---------------- expert gather + weighted sum (bf16 tables, fp32 acc) -----
__global__ __launch_bounds__(256) void expert_k(
    const u16* __restrict__ xb, const u16* __restrict__ downb,
    const u16* __restrict__ upb,
    const int* __restrict__ idx, const float* __restrict__ probs,
    float* __restrict__ es)     // [4096][1024] fp32
{
  __shared__ float acc_s[4][1024];   // 16 KB
  int t = blockIdx.x;
  int w = threadIdx.x >> 6, lane = threadIdx.x & 63;
  const size_t tb = (size_t)t * 1024;
  const int lo = lane * 8;

  B8 xv0, xv1;
  xv0.v = *(const short8*)(xb + tb + lo);
  xv1.v = *(const short8*)(xb + tb + 512 + lo);
  float xf[16];
#pragma unroll
  for (int c = 0; c < 8; ++c) { xf[c] = b2f(xv0.u[c]); xf[8 + c] = b2f(xv1.u[c]); }

  float a[16] = {};
#pragma unroll
  for (int e8 = 0; e8 < 8; ++e8) {
    int e = w * 8 + e8;
    int id = idx[t * 32 + e];
    const u16* dp = downb + (size_t)id * 1024;
    B8 d0, d1;
    d0.v = *(const short8*)(dp + lo);
    d1.v = *(const short8*)(dp + 512 + lo);
    float part = 0.f;
#pragma unroll
    for (int c = 0; c < 8; ++c)
      part += xf[c] * b2f(d0.u[c]) + xf[8 + c] * b2f(d1.u[c]);
#pragma unroll
    for (int off = 32; off; off >>= 1) part += __shfl_xor(part, off);
    float gate = (part / (1.f + __expf(-part))) * probs[t * 32 + e];
    const u16* upp = upb + (size_t)id * 1024;
    B8 u0, u1;
    u0.v = *(const short8*)(upp + lo);
    u1.v = *(const short8*)(upp + 512 + lo);
#pragma unroll
    for (int c = 0; c < 8; ++c) {
      a[c]     += gate * b2f(u0.u[c]);
      a[8 + c] += gate * b2f(u1.u[c]);
    }
  }
#pragma unroll
  for (int c = 0; c < 8; ++c) {
    acc_s[w][lo + c]       = a[c];
    acc_s[w][512 + lo + c] = a[8 + c];
  }
  __syncthreads();
  int d0i = threadIdx.x * 4;
  f32x4 s0 = *(const f32x4*)(&acc_s[0][d0i]);
  f32x4 s1 = *(const f32x4*)(&acc_s[1][d0i]);
  f32x4 s2 = *(const f32x4*)(&acc_s[2][d0i]);
  f32x4 s3 = *(const f32x4*)(&acc_s[3][d0i]);
  f32x4 o;
#pragma unroll
  for (int c = 0; c < 4; ++c) o[c] = (s0[c] + s1[c]) + (s2[c] + s3[c]);
  *(f32x4*)(es + tb + d0i) = o;
}

extern "C" void kernel_launch(void* const* d_in, const int* in_sizes, int n_in,
                              void* d_out, int out_size, void* d_ws, size_t ws_size,
                              hipStream_t stream)
{
  const float* x    = (const float*)d_in[0];
  const float* Wg   = (const float*)d_in[1];
  const float* bg   = (const float*)d_in[2];
  const float* Wu   = (const float*)d_in[3];
  const float* bu   = (const float*)d_in[4];
  const float* Wd   = (const float*)d_in[5];
  const float* bd   = (const float*)d_in[6];
  const float* Wq   = (const float*)d_in[7];
  const float* keys = (const float*)d_in[8];
  const float* down = (const float*)d_in[9];
  const float* up   = (const float*)d_in[10];
  float* out = (float*)d_out;

  // --- workspace layout ---
  const size_t MB = 1048576;
  char* ws = (char*)d_ws;
  u16*   xb    = (u16*)(ws);                 // 8 MB  bf16 x [4096][1024]
  u16*   WgT   = (u16*)(ws + 8  * MB);       // 8 MB  bf16 [4096][1024]
  u16*   WuT   = (u16*)(ws + 16 * MB);       // 8 MB
  u16*   WdT   = (u16*)(ws + 24 * MB);       // 8 MB  bf16 [1024][4096]
  float* es    = (float*)(ws + 32 * MB);     // 16 MB fp32 [4096][1024]
  u16*   WqT   = (u16*)(ws + 32 * MB);       // 1 MB, aliases es head (dead first)
  u16*   qb    = (u16*)(ws + 34 * MB);       // 4 MB, aliases es (dead first)
  int*   idxb  = (int*)(ws + 48 * MB);       // 512 KB
  float* prb   = (float*)(ws + 48 * MB + 512 * 1024);
  u16*   downb = (u16*)(ws + 49 * MB);       // 8 MB bf16 [4096][1024]
  u16*   upb   = (u16*)(ws + 57 * MB);       // 8 MB
  u16*   gb    = (u16*)(ws + 65 * MB);       // chunk_rows x 4096 bf16 (h1)

  size_t avail = ws_size > 65 * MB ? ws_size - 65 * MB : 0;
  int rows = 4096;                           // rows per MLP chunk
  while (rows > 128 && (size_t)rows * 4096 * 2 > avail) rows >>= 1;

  // conversions (fp32 -> bf16; weights fused with transpose)
  cvt_f2b<<<4096, 256, 0, stream>>>(x, xb);
  cvt_f2b<<<4096, 256, 0, stream>>>(down, downb);
  cvt_f2b<<<4096, 256, 0, stream>>>(up, upb);
  convt_w<<<dim3(16, 16),  256, 0, stream>>>(Wq, WqT, 1024, 512);
  convt_w<<<dim3(16, 128), 256, 0, stream>>>(Wg, WgT, 1024, 4096);
  convt_w<<<dim3(16, 128), 256, 0, stream>>>(Wu, WuT, 1024, 4096);
  convt_w<<<dim3(64, 32),  256, 0, stream>>>(Wd, WdT, 4096, 1024);

  // retrieval chain: q = x@Wq -> topk experts -> es
  gemm_bf16<<<dim3(4, 32), 256, 0, stream>>>(xb, WqT, nullptr, nullptr,
                                             qb, nullptr, 4096, 512, 1024);
  retrieve_k<<<4096, 256, 0, stream>>>(qb, keys, idxb, prb);
  expert_k<<<4096, 256, 0, stream>>>(xb, downb, upb, idxb, prb, es);

  // MLP chain, chunked over M: h1 = silu(x@Wg+bg)*(x@Wu+bu); out = h1@Wd+bd+es
  for (int m0c = 0; m0c < 4096; m0c += rows) {
    int gy = rows / 128;
    gemm_gu<<<dim3(32, gy), 256, 0, stream>>>(xb + (size_t)m0c * 1024, WgT, WuT,
                                              bg, bu, gb, rows, 4096, 1024);
    gemm_bf16<<<dim3(8, gy), 256, 0, stream>>>(gb, WdT, bd, es + (size_t)m0c * 1024,
                                               nullptr, out + (size_t)m0c * 1024,
                                               rows, 1024, 4096);
  }
}

// Round 8
// 519.768 us; speedup vs baseline: 1.2791x; 1.1597x over previous
//
#include <hip/hip_runtime.h>
#include <hip/hip_bf16.h>
#include <stdint.h>

typedef unsigned short u16;
typedef __attribute__((ext_vector_type(8))) short short8;   // 8 bf16 (4 VGPRs)
typedef __attribute__((ext_vector_type(4))) float f32x4;

union B8 { short8 v; u16 u[8]; };
union U4 { unsigned long long q; u16 u[4]; };

__device__ __forceinline__ float b2f(u16 b) {
  union { unsigned int i; float f; } x; x.i = ((unsigned int)b) << 16; return x.f;
}
__device__ __forceinline__ u16 f2b(float f) {
  __hip_bfloat16 h = __float2bfloat16(f);
  return *reinterpret_cast<u16*>(&h);
}

// async global->LDS, 16B/lane, LDS dest = wave-uniform base + lane*16 [m97]
#define GLOAD_LDS16(gp, lp)                                                  \
  __builtin_amdgcn_global_load_lds(                                          \
      (const __attribute__((address_space(1))) unsigned int*)(gp),           \
      (__attribute__((address_space(3))) unsigned int*)(lp), 16, 0, 0)

// ---------------- convert fp32 -> bf16 (elementwise, n % 1024 == 0) --------
__global__ __launch_bounds__(256) void cvt_f2b(const float* __restrict__ src,
                                               u16* __restrict__ dst) {
  size_t i = ((size_t)blockIdx.x * 256 + threadIdx.x) * 4;
  f32x4 v = *(const f32x4*)(src + i);
  U4 o;
#pragma unroll
  for (int j = 0; j < 4; ++j) o.u[j] = f2b(v[j]);
  *(unsigned long long*)(dst + i) = o.q;
}

// ---------------- convert + transpose: fp32 W[K][N] -> bf16 WT[N][K] -------
__global__ __launch_bounds__(256) void convt_w(const float* __restrict__ W,
                                               u16* __restrict__ WT,
                                               int K, int N) {
  int k  = blockIdx.x * 64 + (threadIdx.x & 63);
  int n8 = blockIdx.y * 32 + (threadIdx.x >> 6) * 8;
  const float* p = W + (size_t)k * N + n8;
  f32x4 a = *(const f32x4*)(p);
  f32x4 b = *(const f32x4*)(p + 4);
#pragma unroll
  for (int j = 0; j < 4; ++j) WT[(size_t)(n8 + j) * K + k] = f2b(a[j]);
#pragma unroll
  for (int j = 0; j < 4; ++j) WT[(size_t)(n8 + 4 + j) * K + k] = f2b(b[j]);
}

// ---------------- GEMM: C = A[M][K] @ BT[N][K]^T, bf16 in, fp32 acc --------
__global__ __launch_bounds__(256) void gemm_bf16(
    const u16* __restrict__ A, const u16* __restrict__ BT,
    const float* __restrict__ bias,
    u16* __restrict__ Cb, int M, int N, int K)
{
  __shared__ __attribute__((aligned(16))) u16 As[128 * 32];
  __shared__ __attribute__((aligned(16))) u16 Bs[128 * 32];
  int tid = threadIdx.x;
  int m0 = blockIdx.y * 128, n0 = blockIdx.x * 128;
  int wave = tid >> 6, lane = tid & 63;
  int wm = (wave >> 1) * 64, wn = (wave & 1) * 64;
  int quad = lane >> 4, r16 = lane & 15;
  int seg0 = wave * 2, seg1 = wave * 2 + 1;
  int srow = lane >> 2, scol = (lane & 3) * 8;

  const u16* a0 = A  + (size_t)(m0 + seg0 * 16 + srow) * K + scol;
  const u16* a1 = A  + (size_t)(m0 + seg1 * 16 + srow) * K + scol;
  const u16* b0 = BT + (size_t)(n0 + seg0 * 16 + srow) * K + scol;
  const u16* b1 = BT + (size_t)(n0 + seg1 * 16 + srow) * K + scol;

  f32x4 acc[4][4] = {};

  for (int k0 = 0; k0 < K; k0 += 32) {
    GLOAD_LDS16(a0 + k0, As + seg0 * 512);
    GLOAD_LDS16(a1 + k0, As + seg1 * 512);
    GLOAD_LDS16(b0 + k0, Bs + seg0 * 512);
    GLOAD_LDS16(b1 + k0, Bs + seg1 * 512);
    __syncthreads();
    short8 af[4], bfr[4];
#pragma unroll
    for (int i = 0; i < 4; ++i)
      af[i] = *(const short8*)(&As[(wm + i * 16 + r16) * 32 + quad * 8]);
#pragma unroll
    for (int j = 0; j < 4; ++j)
      bfr[j] = *(const short8*)(&Bs[(wn + j * 16 + r16) * 32 + quad * 8]);
#pragma unroll
    for (int i = 0; i < 4; ++i)
#pragma unroll
      for (int j = 0; j < 4; ++j)
        acc[i][j] = __builtin_amdgcn_mfma_f32_16x16x32_bf16(af[i], bfr[j], acc[i][j], 0, 0, 0);
    __syncthreads();
  }

  // C/D layout: col = lane&15, row = quad*4 + reg   [m89-verified]
#pragma unroll
  for (int i = 0; i < 4; ++i) {
    int row = m0 + wm + i * 16 + quad * 4;
#pragma unroll
    for (int j = 0; j < 4; ++j) {
      int col = n0 + wn + j * 16 + r16;
      float bv = bias ? bias[col] : 0.f;
#pragma unroll
      for (int r = 0; r < 4; ++r) {
        float v = acc[i][j][r] + bv;
        Cb[(size_t)(row + r) * N + col] = f2b(v);
      }
    }
  }
}

// -------- split-K down-GEMM: atomicAdd fp32 partials into ES ---------------
// grid (N/128, M/128, K/1024): 4x the blocks of the monolithic N=1024 GEMM
// (which ran at 1 block/CU, fully latency-exposed). ES pre-holds expert_states.
__global__ __launch_bounds__(256) void gemm_dsk(
    const u16* __restrict__ A, const u16* __restrict__ BT,
    float* __restrict__ ES, int M, int N, int K)
{
  __shared__ __attribute__((aligned(16))) u16 As[128 * 32];
  __shared__ __attribute__((aligned(16))) u16 Bs[128 * 32];
  int tid = threadIdx.x;
  int m0 = blockIdx.y * 128, n0 = blockIdx.x * 128;
  int kb = blockIdx.z * 1024, ke = kb + 1024;
  int wave = tid >> 6, lane = tid & 63;
  int wm = (wave >> 1) * 64, wn = (wave & 1) * 64;
  int quad = lane >> 4, r16 = lane & 15;
  int seg0 = wave * 2, seg1 = wave * 2 + 1;
  int srow = lane >> 2, scol = (lane & 3) * 8;

  const u16* a0 = A  + (size_t)(m0 + seg0 * 16 + srow) * K + scol;
  const u16* a1 = A  + (size_t)(m0 + seg1 * 16 + srow) * K + scol;
  const u16* b0 = BT + (size_t)(n0 + seg0 * 16 + srow) * K + scol;
  const u16* b1 = BT + (size_t)(n0 + seg1 * 16 + srow) * K + scol;

  f32x4 acc[4][4] = {};

  for (int k0 = kb; k0 < ke; k0 += 32) {
    GLOAD_LDS16(a0 + k0, As + seg0 * 512);
    GLOAD_LDS16(a1 + k0, As + seg1 * 512);
    GLOAD_LDS16(b0 + k0, Bs + seg0 * 512);
    GLOAD_LDS16(b1 + k0, Bs + seg1 * 512);
    __syncthreads();
    short8 af[4], bfr[4];
#pragma unroll
    for (int i = 0; i < 4; ++i)
      af[i] = *(const short8*)(&As[(wm + i * 16 + r16) * 32 + quad * 8]);
#pragma unroll
    for (int j = 0; j < 4; ++j)
      bfr[j] = *(const short8*)(&Bs[(wn + j * 16 + r16) * 32 + quad * 8]);
#pragma unroll
    for (int i = 0; i < 4; ++i)
#pragma unroll
      for (int j = 0; j < 4; ++j)
        acc[i][j] = __builtin_amdgcn_mfma_f32_16x16x32_bf16(af[i], bfr[j], acc[i][j], 0, 0, 0);
    __syncthreads();
  }

#pragma unroll
  for (int i = 0; i < 4; ++i) {
    int row = m0 + wm + i * 16 + quad * 4;
#pragma unroll
    for (int j = 0; j < 4; ++j) {
      int col = n0 + wn + j * 16 + r16;
#pragma unroll
      for (int r = 0; r < 4; ++r)
        atomicAdd(&ES[(size_t)(row + r) * N + col], acc[i][j][r]);
    }
  }
}

// ---------------- epilogue: out = es + bd (N = 1024) -----------------------
__global__ __launch_bounds__(256) void add_bias_k(const float* __restrict__ es,
                                                  const float* __restrict__ bd,
                                                  float* __restrict__ out) {
  int t = blockIdx.x, c0 = threadIdx.x * 4;
  f32x4 e = *(const f32x4*)(es + (size_t)t * 1024 + c0);
  f32x4 b = *(const f32x4*)(bd + c0);
  f32x4 o;
#pragma unroll
  for (int c = 0; c < 4; ++c) o[c] = e[c] + b[c];
  *(f32x4*)(out + (size_t)t * 1024 + c0) = o;
}

// ------- fused gate+up GEMM: H = silu(A@Bg^T + bg) * (A@Bu^T + bu) ---------
// __launch_bounds__(256,2): cap VGPR+AGPR <= 256 so 2 waves/SIMD co-reside
// (acc alone = 128 AGPR; at default alloc we measured 1 block/CU, 11.5% occ).
__global__ __launch_bounds__(256, 2) void gemm_gu(
    const u16* __restrict__ A, const u16* __restrict__ BgT,
    const u16* __restrict__ BuT,
    const float* __restrict__ bg, const float* __restrict__ bu,
    u16* __restrict__ H, int M, int N, int K)
{
  __shared__ __attribute__((aligned(16))) u16 As[128 * 32];
  __shared__ __attribute__((aligned(16))) u16 Gs[128 * 32];
  __shared__ __attribute__((aligned(16))) u16 Us[128 * 32];
  int tid = threadIdx.x;
  int m0 = blockIdx.y * 128, n0 = blockIdx.x * 128;
  int wave = tid >> 6, lane = tid & 63;
  int wm = (wave >> 1) * 64, wn = (wave & 1) * 64;
  int quad = lane >> 4, r16 = lane & 15;
  int seg0 = wave * 2, seg1 = wave * 2 + 1;
  int srow = lane >> 2, scol = (lane & 3) * 8;

  const u16* a0 = A   + (size_t)(m0 + seg0 * 16 + srow) * K + scol;
  const u16* a1 = A   + (size_t)(m0 + seg1 * 16 + srow) * K + scol;
  const u16* g0 = BgT + (size_t)(n0 + seg0 * 16 + srow) * K + scol;
  const u16* g1 = BgT + (size_t)(n0 + seg1 * 16 + srow) * K + scol;
  const u16* u0 = BuT + (size_t)(n0 + seg0 * 16 + srow) * K + scol;
  const u16* u1 = BuT + (size_t)(n0 + seg1 * 16 + srow) * K + scol;

  f32x4 ag[4][4] = {}, au[4][4] = {};

  for (int k0 = 0; k0 < K; k0 += 32) {
    GLOAD_LDS16(a0 + k0, As + seg0 * 512);
    GLOAD_LDS16(a1 + k0, As + seg1 * 512);
    GLOAD_LDS16(g0 + k0, Gs + seg0 * 512);
    GLOAD_LDS16(g1 + k0, Gs + seg1 * 512);
    GLOAD_LDS16(u0 + k0, Us + seg0 * 512);
    GLOAD_LDS16(u1 + k0, Us + seg1 * 512);
    __syncthreads();
    short8 af[4], bfr[4];
#pragma unroll
    for (int i = 0; i < 4; ++i)
      af[i] = *(const short8*)(&As[(wm + i * 16 + r16) * 32 + quad * 8]);
#pragma unroll
    for (int j = 0; j < 4; ++j)
      bfr[j] = *(const short8*)(&Gs[(wn + j * 16 + r16) * 32 + quad * 8]);
#pragma unroll
    for (int i = 0; i < 4; ++i)
#pragma unroll
      for (int j = 0; j < 4; ++j)
        ag[i][j] = __builtin_amdgcn_mfma_f32_16x16x32_bf16(af[i], bfr[j], ag[i][j], 0, 0, 0);
#pragma unroll
    for (int j = 0; j < 4; ++j)
      bfr[j] = *(const short8*)(&Us[(wn + j * 16 + r16) * 32 + quad * 8]);
#pragma unroll
    for (int i = 0; i < 4; ++i)
#pragma unroll
      for (int j = 0; j < 4; ++j)
        au[i][j] = __builtin_amdgcn_mfma_f32_16x16x32_bf16(af[i], bfr[j], au[i][j], 0, 0, 0);
    __syncthreads();
  }

#pragma unroll
  for (int i = 0; i < 4; ++i) {
    int row = m0 + wm + i * 16 + quad * 4;
#pragma unroll
    for (int j = 0; j < 4; ++j) {
      int col = n0 + wn + j * 16 + r16;
      float bgv = bg[col], buv = bu[col];
#pragma unroll
      for (int r = 0; r < 4; ++r) {
        float g = ag[i][j][r] + bgv;
        float u = au[i][j][r] + buv;
        float h = (g / (1.f + __expf(-g))) * u;
        H[(size_t)(row + r) * N + col] = f2b(h);
      }
    }
  }
}

// ---------------- product-key retrieval (wave-parallel butterfly top-k) ----
__global__ __launch_bounds__(256) void retrieve_k(
    const u16*  __restrict__ q,     // bf16 [4096][512] = [t][p(2)][h(4)][n(64)]
    const float* __restrict__ keys, // fp32 [4][64][2][64]
    int* __restrict__ idx_out,      // [4096][4][8]
    float* __restrict__ p_out)      // [4096][4][8]
{
  __shared__ float tv[4][2][8];
  __shared__ int   ti[4][2][8];
  int t = blockIdx.x;
  int w = threadIdx.x >> 6, lane = threadIdx.x & 63;

#pragma unroll
  for (int p = 0; p < 2; ++p) {
    const u16*   qp = q + (size_t)t * 512 + p * 256 + w * 64;
    const float* kp = keys + (size_t)((w * 64 + lane) * 2 + p) * 64;
    float s = 0.f;
#pragma unroll
    for (int n = 0; n < 64; n += 8) {
      B8 qv; qv.v = *(const short8*)(qp + n);
      f32x4 k0 = *(const f32x4*)(kp + n);
      f32x4 k1 = *(const f32x4*)(kp + n + 4);
#pragma unroll
      for (int c = 0; c < 4; ++c) s += b2f(qv.u[c]) * k0[c];
#pragma unroll
      for (int c = 0; c < 4; ++c) s += b2f(qv.u[4 + c]) * k1[c];
    }
    float v = s; int vi = lane;
#pragma unroll
    for (int r = 0; r < 8; ++r) {
      float mv = v; int mi = vi;
#pragma unroll
      for (int off = 32; off; off >>= 1) {
        float ov = __shfl_xor(mv, off);
        int   oi = __shfl_xor(mi, off);
        if (ov > mv || (ov == mv && oi < mi)) { mv = ov; mi = oi; }
      }
      if (lane == 0) { tv[w][p][r] = mv; ti[w][p][r] = mi; }
      if (vi == mi) v = -3.0e38f;
    }
  }
  __syncthreads();
  float v2 = tv[w][0][lane >> 3] + tv[w][1][lane & 7];
  int vi2 = lane;
  float s8[8]; int x8[8];
#pragma unroll
  for (int r = 0; r < 8; ++r) {
    float mv = v2; int mi = vi2;
#pragma unroll
    for (int off = 32; off; off >>= 1) {
      float ov = __shfl_xor(mv, off);
      int   oi = __shfl_xor(mi, off);
      if (ov > mv || (ov == mv && oi < mi)) { mv = ov; mi = oi; }
    }
    s8[r] = mv;
    x8[r] = ti[w][0][mi >> 3] * 64 + ti[w][1][mi & 7];
    if (vi2 == mi) v2 = -3.0e38f;
  }
  if (lane == 0) {
    float m = s8[0], sum = 0.f;
#pragma unroll
    for (int r = 0; r < 8; ++r) sum += __expf(s8[r] - m);
#pragma unroll
    for (int r = 0; r < 8; ++r) {
      int o = (t * 4 + w) * 8 + r;
      p_out[o]   = __expf(s8[r] - m) / sum;
      idx_out[o] = x8[r];
    }
  }
}

// ---------------- expert gather + weighted sum (bf16 tables, fp32 acc) -----
__global__ __launch_bounds__(256) void expert_k(
    const u16* __restrict__ xb, const u16* __restrict__ downb,
    const u16* __restrict__ upb,
    const int* __restrict__ idx, const float* __restrict__ probs,
    float* __restrict__ es)     // [4096][1024] fp32
{
  __shared__ float acc_s[4][1024];   // 16 KB
  int t = blockIdx.x;
  int w = threadIdx.x >> 6, lane = threadIdx.x & 63;
  const size_t tb = (size_t)t * 1024;
  const int lo = lane * 8;

  B8 xv0, xv1;
  xv0.v = *(const short8*)(xb + tb + lo);
  xv1.v = *(const short8*)(xb + tb + 512 + lo);
  float xf[16];
#pragma unroll
  for (int c = 0; c < 8; ++c) { xf[c] = b2f(xv0.u[c]); xf[8 + c] = b2f(xv1.u[c]); }

  float a[16] = {};
#pragma unroll
  for (int e8 = 0; e8 < 8; ++e8) {
    int e = w * 8 + e8;
    int id = idx[t * 32 + e];
    const u16* dp = downb + (size_t)id * 1024;
    B8 d0, d1;
    d0.v = *(const short8*)(dp + lo);
    d1.v = *(const short8*)(dp + 512 + lo);
    float part = 0.f;
#pragma unroll
    for (int c = 0; c < 8; ++c)
      part += xf[c] * b2f(d0.u[c]) + xf[8 + c] * b2f(d1.u[c]);
#pragma unroll
    for (int off = 32; off; off >>= 1) part += __shfl_xor(part, off);
    float gate = (part / (1.f + __expf(-part))) * probs[t * 32 + e];
    const u16* upp = upb + (size_t)id * 1024;
    B8 u0, u1;
    u0.v = *(const short8*)(upp + lo);
    u1.v = *(const short8*)(upp + 512 + lo);
#pragma unroll
    for (int c = 0; c < 8; ++c) {
      a[c]     += gate * b2f(u0.u[c]);
      a[8 + c] += gate * b2f(u1.u[c]);
    }
  }
#pragma unroll
  for (int c = 0; c < 8; ++c) {
    acc_s[w][lo + c]       = a[c];
    acc_s[w][512 + lo + c] = a[8 + c];
  }
  __syncthreads();
  int d0i = threadIdx.x * 4;
  f32x4 s0 = *(const f32x4*)(&acc_s[0][d0i]);
  f32x4 s1 = *(const f32x4*)(&acc_s[1][d0i]);
  f32x4 s2 = *(const f32x4*)(&acc_s[2][d0i]);
  f32x4 s3 = *(const f32x4*)(&acc_s[3][d0i]);
  f32x4 o;
#pragma unroll
  for (int c = 0; c < 4; ++c) o[c] = (s0[c] + s1[c]) + (s2[c] + s3[c]);
  *(f32x4*)(es + tb + d0i) = o;
}

extern "C" void kernel_launch(void* const* d_in, const int* in_sizes, int n_in,
                              void* d_out, int out_size, void* d_ws, size_t ws_size,
                              hipStream_t stream)
{
  const float* x    = (const float*)d_in[0];
  const float* Wg   = (const float*)d_in[1];
  const float* bg   = (const float*)d_in[2];
  const float* Wu   = (const float*)d_in[3];
  const float* bu   = (const float*)d_in[4];
  const float* Wd   = (const float*)d_in[5];
  const float* bd   = (const float*)d_in[6];
  const float* Wq   = (const float*)d_in[7];
  const float* keys = (const float*)d_in[8];
  const float* down = (const float*)d_in[9];
  const float* up   = (const float*)d_in[10];
  float* out = (float*)d_out;

  // --- workspace layout ---
  const size_t MB = 1048576;
  char* ws = (char*)d_ws;
  u16*   xb    = (u16*)(ws);                 // 8 MB  bf16 x [4096][1024]
  u16*   WgT   = (u16*)(ws + 8  * MB);       // 8 MB  bf16 [4096][1024]
  u16*   WuT   = (u16*)(ws + 16 * MB);       // 8 MB
  u16*   WdT   = (u16*)(ws + 24 * MB);       // 8 MB  bf16 [1024][4096]
  float* es    = (float*)(ws + 32 * MB);     // 16 MB fp32 [4096][1024]
  u16*   WqT   = (u16*)(ws + 32 * MB);       // 1 MB, aliases es head (dead first)
  u16*   qb    = (u16*)(ws + 34 * MB);       // 4 MB, aliases es (dead first)
  int*   idxb  = (int*)(ws + 48 * MB);       // 512 KB
  float* prb   = (float*)(ws + 48 * MB + 512 * 1024);
  u16*   downb = (u16*)(ws + 49 * MB);       // 8 MB bf16 [4096][1024]
  u16*   upb   = (u16*)(ws + 57 * MB);       // 8 MB
  u16*   gb    = (u16*)(ws + 65 * MB);       // chunk_rows x 4096 bf16 (h1)

  size_t avail = ws_size > 65 * MB ? ws_size - 65 * MB : 0;
  int rows = 4096;                           // rows per MLP chunk
  while (rows > 128 && (size_t)rows * 4096 * 2 > avail) rows >>= 1;

  // conversions (fp32 -> bf16; weights fused with transpose)
  cvt_f2b<<<4096, 256, 0, stream>>>(x, xb);
  cvt_f2b<<<4096, 256, 0, stream>>>(down, downb);
  cvt_f2b<<<4096, 256, 0, stream>>>(up, upb);
  convt_w<<<dim3(16, 16),  256, 0, stream>>>(Wq, WqT, 1024, 512);
  convt_w<<<dim3(16, 128), 256, 0, stream>>>(Wg, WgT, 1024, 4096);
  convt_w<<<dim3(16, 128), 256, 0, stream>>>(Wu, WuT, 1024, 4096);
  convt_w<<<dim3(64, 32),  256, 0, stream>>>(Wd, WdT, 4096, 1024);

  // retrieval chain: q = x@Wq -> topk experts -> es
  gemm_bf16<<<dim3(4, 32), 256, 0, stream>>>(xb, WqT, nullptr,
                                             qb, 4096, 512, 1024);
  retrieve_k<<<4096, 256, 0, stream>>>(qb, keys, idxb, prb);
  expert_k<<<4096, 256, 0, stream>>>(xb, downb, upb, idxb, prb, es);

  // MLP chain: h1 = silu(x@Wg+bg)*(x@Wu+bu); es += h1@Wd (split-K); out = es+bd
  for (int m0c = 0; m0c < 4096; m0c += rows) {
    int gy = rows / 128;
    gemm_gu<<<dim3(32, gy), 256, 0, stream>>>(xb + (size_t)m0c * 1024, WgT, WuT,
                                              bg, bu, gb, rows, 4096, 1024);
    gemm_dsk<<<dim3(8, gy, 4), 256, 0, stream>>>(gb, WdT, es + (size_t)m0c * 1024,
                                                 rows, 1024, 4096);
  }
  add_bias_k<<<4096, 256, 0, stream>>>(es, bd, out);
}